// Round 1
// baseline (909.166 us; speedup 1.0000x reference)
//
#include <hip/hip_runtime.h>
#include <math.h>

#define N_NODES 100000
#define N_EDGES 1600000
#define F_INP 64
#define H_DIM 64
#define C_DIM 40

// ---------- degree / normalization ----------
__global__ __launch_bounds__(256) void k_deg_init(float* deg) {
    int i = blockIdx.x * 256 + threadIdx.x;
    if (i < N_NODES) deg[i] = 1.0f;  // self-loop weight
}

__global__ __launch_bounds__(256) void k_deg_accum(const int* __restrict__ ei,
                                                   const float* __restrict__ w,
                                                   float* deg) {
    int e = blockIdx.x * 256 + threadIdx.x;
    if (e < N_EDGES) atomicAdd(&deg[ei[N_EDGES + e]], w[e]);
}

__global__ __launch_bounds__(256) void k_dinv(float* deg) {
    int i = blockIdx.x * 256 + threadIdx.x;
    if (i < N_NODES) deg[i] = rsqrtf(deg[i]);  // deg >= 1 always
}

// ---------- h1 = x @ W1  (block: 256 thr = 4 rows x 64 cols) ----------
__global__ __launch_bounds__(256) void k_mm1(const float* __restrict__ x,
                                             const float* __restrict__ W1,
                                             float* __restrict__ h1) {
    __shared__ float Ws[64 * 64];
    __shared__ float xs[4][64];
    int t = threadIdx.x;
    for (int i = t; i < 64 * 64; i += 256) Ws[i] = W1[i];
    int rl = t >> 6, c = t & 63;
    int r = blockIdx.x * 4 + rl;
    if (r < N_NODES) xs[rl][c] = x[r * 64 + c];
    __syncthreads();
    if (r < N_NODES) {
        float acc = 0.f;
#pragma unroll
        for (int k = 0; k < 64; ++k) acc = fmaf(xs[rl][k], Ws[k * 64 + c], acc);
        h1[r * 64 + c] = acc;
    }
}

// ---------- agg1 init with self-loop: h1[i]*dinv[i]^2 ----------
__global__ __launch_bounds__(256) void k_selfloop1(const float* __restrict__ h1,
                                                   const float* __restrict__ dinv,
                                                   float* __restrict__ agg1) {
    int idx = blockIdx.x * 256 + threadIdx.x;
    if (idx < N_NODES * 64) {
        float d = dinv[idx >> 6];
        agg1[idx] = h1[idx] * d * d;
    }
}

// ---------- edge scatter layer 1: one wave per edge, lane = column ----------
__global__ __launch_bounds__(256) void k_edge1(const int* __restrict__ ei,
                                               const float* __restrict__ w,
                                               const float* __restrict__ dinv,
                                               const float* __restrict__ h1,
                                               float* agg1) {
    int t = blockIdx.x * 256 + threadIdx.x;
    int e = t >> 6, c = t & 63;
    if (e < N_EDGES) {
        int s = ei[e], d = ei[N_EDGES + e];
        float coeff = dinv[s] * w[e] * dinv[d];
        atomicAdd(&agg1[d * 64 + c], h1[s * 64 + c] * coeff);
    }
}

// ---------- h2 = relu(agg1 + b1) @ W2  (block: 320 thr = 8 rows x 40 cols) ----------
__global__ __launch_bounds__(320) void k_mm2(const float* __restrict__ agg1,
                                             const float* __restrict__ b1,
                                             const float* __restrict__ W2,
                                             float* __restrict__ h2) {
    __shared__ float Ws[64 * 40];
    __shared__ float as[8][64];
    __shared__ float bs[64];
    int t = threadIdx.x;  // 0..319
    for (int i = t; i < 64 * 40; i += 320) Ws[i] = W2[i];
    if (t < 64) bs[t] = b1[t];
    __syncthreads();
    for (int i = t; i < 8 * 64; i += 320) {
        int rl = i >> 6, k = i & 63;
        int row = blockIdx.x * 8 + rl;
        as[rl][k] = (row < N_NODES) ? fmaxf(agg1[row * 64 + k] + bs[k], 0.f) : 0.f;
    }
    __syncthreads();
    int rl = t / 40, j = t - rl * 40;
    int row = blockIdx.x * 8 + rl;
    if (row < N_NODES) {
        float acc = 0.f;
#pragma unroll
        for (int k = 0; k < 64; ++k) acc = fmaf(as[rl][k], Ws[k * 40 + j], acc);
        h2[row * 40 + j] = acc;
    }
}

// ---------- out init with self-loop: h2[i]*dinv[i]^2 ----------
__global__ __launch_bounds__(256) void k_selfloop2(const float* __restrict__ h2,
                                                   const float* __restrict__ dinv,
                                                   float* __restrict__ out) {
    int idx = blockIdx.x * 256 + threadIdx.x;
    if (idx < N_NODES * 40) {
        float d = dinv[idx / 40];
        out[idx] = h2[idx] * d * d;
    }
}

// ---------- edge scatter layer 2: 8 edges x 40 cols per 320-thread block ----------
__global__ __launch_bounds__(320) void k_edge2(const int* __restrict__ ei,
                                               const float* __restrict__ w,
                                               const float* __restrict__ dinv,
                                               const float* __restrict__ h2,
                                               float* out) {
    int t = threadIdx.x;
    int el = t / 40, j = t - el * 40;
    int e = blockIdx.x * 8 + el;
    if (e < N_EDGES) {
        int s = ei[e], d = ei[N_EDGES + e];
        float coeff = dinv[s] * w[e] * dinv[d];
        atomicAdd(&out[d * 40 + j], h2[s * 40 + j] * coeff);
    }
}

// ---------- bias + log_softmax in place on out (wave per row, 40 cols) ----------
__global__ __launch_bounds__(256) void k_lsm(float* out, const float* __restrict__ b2) {
    int t = threadIdx.x;
    int row = blockIdx.x * 4 + (t >> 6);
    int lane = t & 63;
    if (row >= N_NODES) return;
    float v = (lane < 40) ? out[row * 40 + lane] + b2[lane] : -INFINITY;
    float m = v;
#pragma unroll
    for (int off = 32; off; off >>= 1) m = fmaxf(m, __shfl_xor(m, off, 64));
    float ex = (lane < 40) ? expf(v - m) : 0.f;
    float s = ex;
#pragma unroll
    for (int off = 32; off; off >>= 1) s += __shfl_xor(s, off, 64);
    if (lane < 40) out[row * 40 + lane] = v - m - logf(s);
}

extern "C" void kernel_launch(void* const* d_in, const int* in_sizes, int n_in,
                              void* d_out, int out_size, void* d_ws, size_t ws_size,
                              hipStream_t stream) {
    const float* x  = (const float*)d_in[0];
    const int*   ei = (const int*)d_in[1];
    const float* w  = (const float*)d_in[2];
    const float* W1 = (const float*)d_in[3];
    const float* b1 = (const float*)d_in[4];
    const float* W2 = (const float*)d_in[5];
    const float* b2 = (const float*)d_in[6];
    float* out = (float*)d_out;

    // workspace layout (floats): deg/dinv | h1 | agg1 | h2
    float* ws   = (float*)d_ws;
    float* deg  = ws;                               // N
    float* h1   = deg + N_NODES;                    // N*64
    float* agg1 = h1 + N_NODES * 64;                // N*64
    float* h2   = agg1 + N_NODES * 64;              // N*40

    // degree + dinv
    k_deg_init<<<(N_NODES + 255) / 256, 256, 0, stream>>>(deg);
    k_deg_accum<<<(N_EDGES + 255) / 256, 256, 0, stream>>>(ei, w, deg);
    k_dinv<<<(N_NODES + 255) / 256, 256, 0, stream>>>(deg);

    // layer 1
    k_mm1<<<(N_NODES + 3) / 4, 256, 0, stream>>>(x, W1, h1);
    k_selfloop1<<<(N_NODES * 64 + 255) / 256, 256, 0, stream>>>(h1, deg, agg1);
    k_edge1<<<(N_EDGES * 64 + 255) / 256, 256, 0, stream>>>(ei, w, deg, h1, agg1);

    // layer 2
    k_mm2<<<(N_NODES + 7) / 8, 320, 0, stream>>>(agg1, b1, W2, h2);
    k_selfloop2<<<(N_NODES * 40 + 255) / 256, 256, 0, stream>>>(h2, deg, out);
    k_edge2<<<(N_EDGES + 7) / 8, 320, 0, stream>>>(ei, w, deg, h2, out);

    // epilogue
    k_lsm<<<(N_NODES + 3) / 4, 256, 0, stream>>>(out, b2);
}

// Round 2
// 602.923 us; speedup vs baseline: 1.5079x; 1.5079x over previous
//
#include <hip/hip_runtime.h>
#include <math.h>

#define N_NODES 100000
#define N_EDGES 1600000
#define F_INP 64
#define H_DIM 64
#define C_DIM 40

// ---------------- workspace layout (4-byte units) ----------------
// deg/dinv : [0, 100000)                float
// rowStart : [100000, 200001)           int (N+1)
// cursor   : [200002, 300002)           int
// counts   : [300002, 400002)           int
// bsum     : [400002, 400100)           int (98)
// boff     : [400100, 400198)           int (98)
// edgebuf  : [400200, 3600200)          int2 x E (8B aligned: 400200*4 % 8 == 0)
// h1 / h2  : [3600200, 10000200)        float (N*64; h2 aliases h1)
// agg1     : [10000200, 16400200)       float (N*64)
#define OFF_DEG   0
#define OFF_ROW   100000
#define OFF_CUR   200002
#define OFF_CNT   300002
#define OFF_BSUM  400002
#define OFF_BOFF  400100
#define OFF_EDGE  400200
#define OFF_H1    3600200
#define OFF_AGG1  10000200

#define SCAN_CHUNK 1024
#define SCAN_NBLK  ((N_NODES + SCAN_CHUNK - 1) / SCAN_CHUNK)  // 98

__device__ inline float rlane(float v, int k) {
    return __int_as_float(__builtin_amdgcn_readlane(__float_as_int(v), k));
}

// ---------- init: deg=1 (self loop), counts=0 ----------
__global__ __launch_bounds__(256) void k_init(float* deg, int* counts) {
    int i = blockIdx.x * 256 + threadIdx.x;
    if (i < N_NODES) { deg[i] = 1.0f; counts[i] = 0; }
}

// ---------- histogram: deg[dst]+=w, counts[dst]++ ----------
__global__ __launch_bounds__(256) void k_hist(const int* __restrict__ ei,
                                              const float* __restrict__ w,
                                              float* deg, int* counts) {
    int e = blockIdx.x * 256 + threadIdx.x;
    if (e < N_EDGES) {
        int d = ei[N_EDGES + e];
        atomicAdd(&deg[d], w[e]);
        atomicAdd(&counts[d], 1);
    }
}

__global__ __launch_bounds__(256) void k_dinv(float* deg) {
    int i = blockIdx.x * 256 + threadIdx.x;
    if (i < N_NODES) deg[i] = rsqrtf(deg[i]);
}

// ---------- scan stage 1: per-1024-chunk sums ----------
__global__ __launch_bounds__(256) void k_scan1(const int* __restrict__ counts, int* bsum) {
    __shared__ int sd[256];
    int t = threadIdx.x, base = blockIdx.x * SCAN_CHUNK;
    int s = 0;
#pragma unroll
    for (int i = 0; i < 4; ++i) {
        int idx = base + t * 4 + i;
        if (idx < N_NODES) s += counts[idx];
    }
    sd[t] = s; __syncthreads();
    for (int off = 128; off > 0; off >>= 1) {
        if (t < off) sd[t] += sd[t + off];
        __syncthreads();
    }
    if (t == 0) bsum[blockIdx.x] = sd[0];
}

// ---------- scan stage 2: exclusive scan of 98 partials (1 block, 128 thr) ----------
__global__ __launch_bounds__(128) void k_scan2(const int* __restrict__ bsum, int* boff,
                                               int* rowStart) {
    __shared__ int sd[128];
    int t = threadIdx.x;
    sd[t] = (t < SCAN_NBLK) ? bsum[t] : 0;
    __syncthreads();
#pragma unroll
    for (int off = 1; off < 128; off <<= 1) {
        int v = (t >= off) ? sd[t - off] : 0;
        __syncthreads();
        sd[t] += v;
        __syncthreads();
    }
    if (t < SCAN_NBLK) boff[t] = (t == 0) ? 0 : sd[t - 1];
    if (t == SCAN_NBLK - 1) rowStart[N_NODES] = sd[t];  // == E
}

// ---------- scan stage 3: write rowStart + cursor ----------
__global__ __launch_bounds__(256) void k_scan3(const int* __restrict__ counts,
                                               const int* __restrict__ boff,
                                               int* rowStart, int* cursor) {
    __shared__ int sd[256];
    int t = threadIdx.x, base = blockIdx.x * SCAN_CHUNK;
    int c[4]; int s = 0;
#pragma unroll
    for (int i = 0; i < 4; ++i) {
        int idx = base + t * 4 + i;
        c[i] = (idx < N_NODES) ? counts[idx] : 0;
        s += c[i];
    }
    int tsum = s;
    sd[t] = s; __syncthreads();
#pragma unroll
    for (int off = 1; off < 256; off <<= 1) {
        int v = (t >= off) ? sd[t - off] : 0;
        __syncthreads();
        sd[t] += v;
        __syncthreads();
    }
    int run = boff[blockIdx.x] + sd[t] - tsum;  // exclusive prefix for this thread
#pragma unroll
    for (int i = 0; i < 4; ++i) {
        int idx = base + t * 4 + i;
        if (idx < N_NODES) {
            rowStart[idx] = run;
            cursor[idx] = run;
            run += c[i];
        }
    }
}

// ---------- scatter edges into CSR: (src, coeff) packed int2 ----------
__global__ __launch_bounds__(256) void k_scatter(const int* __restrict__ ei,
                                                 const float* __restrict__ w,
                                                 const float* __restrict__ dinv,
                                                 int* cursor, int2* edgebuf) {
    int e = blockIdx.x * 256 + threadIdx.x;
    if (e < N_EDGES) {
        int s = ei[e], d = ei[N_EDGES + e];
        float coeff = dinv[s] * w[e] * dinv[d];
        int pos = atomicAdd(&cursor[d], 1);
        edgebuf[pos] = make_int2(s, __float_as_int(coeff));
    }
}

// ---------- h1 = x @ W1 : W column in regs, readlane broadcast, 4 rows/iter ----------
__global__ __launch_bounds__(256) void k_mm1(const float* __restrict__ x,
                                             const float* __restrict__ W1,
                                             float* __restrict__ h1) {
    int t = threadIdx.x, lane = t & 63, wv = t >> 6;
    int wid = blockIdx.x * 4 + wv, nw = gridDim.x * 4;
    float Wc[64];
#pragma unroll
    for (int k = 0; k < 64; ++k) Wc[k] = W1[k * 64 + lane];
    for (int r0 = wid * 4; r0 < N_NODES; r0 += nw * 4) {
        float x0 = x[(r0 + 0) * 64 + lane];
        float x1 = x[(r0 + 1) * 64 + lane];
        float x2 = x[(r0 + 2) * 64 + lane];
        float x3 = x[(r0 + 3) * 64 + lane];
        float a0 = 0.f, a1 = 0.f, a2 = 0.f, a3 = 0.f;
#pragma unroll
        for (int k = 0; k < 64; ++k) {
            float wk = Wc[k];
            a0 = fmaf(rlane(x0, k), wk, a0);
            a1 = fmaf(rlane(x1, k), wk, a1);
            a2 = fmaf(rlane(x2, k), wk, a2);
            a3 = fmaf(rlane(x3, k), wk, a3);
        }
        h1[(r0 + 0) * 64 + lane] = a0;
        h1[(r0 + 1) * 64 + lane] = a1;
        h1[(r0 + 2) * 64 + lane] = a2;
        h1[(r0 + 3) * 64 + lane] = a3;
    }
}

// ---------- agg1: CSR gather, wave per node, lane = col (64) ----------
__global__ __launch_bounds__(256) void k_agg1(const int* __restrict__ rowStart,
                                              const int2* __restrict__ edgebuf,
                                              const float* __restrict__ dinv,
                                              const float* __restrict__ h1,
                                              float* __restrict__ agg1) {
    int t = threadIdx.x, lane = t & 63;
    int node = blockIdx.x * 4 + (t >> 6);
    if (node >= N_NODES) return;
    float dn = dinv[node];
    float acc = h1[node * 64 + lane] * dn * dn;  // self loop
    int s0 = rowStart[node], s1 = rowStart[node + 1];
    for (int base = s0; base < s1; base += 64) {
        int idx = base + lane;
        int2 ev = (idx < s1) ? edgebuf[idx] : make_int2(0, 0);
        int cnt = min(64, s1 - base);
        for (int j = 0; j < cnt; ++j) {
            int ss = __shfl(ev.x, j, 64);
            float cc = __int_as_float(__shfl(ev.y, j, 64));
            acc = fmaf(h1[ss * 64 + lane], cc, acc);
        }
    }
    agg1[node * 64 + lane] = acc;
}

// ---------- h2 = relu(agg1+b1) @ W2 ----------
__global__ __launch_bounds__(256) void k_mm2(const float* __restrict__ agg1,
                                             const float* __restrict__ b1,
                                             const float* __restrict__ W2,
                                             float* __restrict__ h2) {
    int t = threadIdx.x, lane = t & 63, wv = t >> 6;
    int wid = blockIdx.x * 4 + wv, nw = gridDim.x * 4;
    bool act = lane < C_DIM;
    float Wc[64];
#pragma unroll
    for (int k = 0; k < 64; ++k) Wc[k] = act ? W2[k * C_DIM + lane] : 0.f;
    float bv = b1[lane];
    for (int r0 = wid * 4; r0 < N_NODES; r0 += nw * 4) {
        float x0 = fmaxf(agg1[(r0 + 0) * 64 + lane] + bv, 0.f);
        float x1 = fmaxf(agg1[(r0 + 1) * 64 + lane] + bv, 0.f);
        float x2 = fmaxf(agg1[(r0 + 2) * 64 + lane] + bv, 0.f);
        float x3 = fmaxf(agg1[(r0 + 3) * 64 + lane] + bv, 0.f);
        float a0 = 0.f, a1 = 0.f, a2 = 0.f, a3 = 0.f;
#pragma unroll
        for (int k = 0; k < 64; ++k) {
            float wk = Wc[k];
            a0 = fmaf(rlane(x0, k), wk, a0);
            a1 = fmaf(rlane(x1, k), wk, a1);
            a2 = fmaf(rlane(x2, k), wk, a2);
            a3 = fmaf(rlane(x3, k), wk, a3);
        }
        if (act) {
            h2[(r0 + 0) * C_DIM + lane] = a0;
            h2[(r0 + 1) * C_DIM + lane] = a1;
            h2[(r0 + 2) * C_DIM + lane] = a2;
            h2[(r0 + 3) * C_DIM + lane] = a3;
        }
    }
}

// ---------- agg2 + bias + log_softmax fused, wave per node ----------
__global__ __launch_bounds__(256) void k_agg2(const int* __restrict__ rowStart,
                                              const int2* __restrict__ edgebuf,
                                              const float* __restrict__ dinv,
                                              const float* __restrict__ h2,
                                              const float* __restrict__ b2,
                                              float* __restrict__ out) {
    int t = threadIdx.x, lane = t & 63;
    int node = blockIdx.x * 4 + (t >> 6);
    if (node >= N_NODES) return;
    bool act = lane < C_DIM;
    float dn = dinv[node];
    float acc = act ? h2[node * C_DIM + lane] * dn * dn : 0.f;  // self loop
    int s0 = rowStart[node], s1 = rowStart[node + 1];
    for (int base = s0; base < s1; base += 64) {
        int idx = base + lane;
        int2 ev = (idx < s1) ? edgebuf[idx] : make_int2(0, 0);
        int cnt = min(64, s1 - base);
        for (int j = 0; j < cnt; ++j) {
            int ss = __shfl(ev.x, j, 64);
            float cc = __int_as_float(__shfl(ev.y, j, 64));
            float hv = act ? h2[ss * C_DIM + lane] : 0.f;
            acc = fmaf(hv, cc, acc);
        }
    }
    float v = act ? acc + b2[lane] : -INFINITY;
    float m = v;
#pragma unroll
    for (int off = 32; off; off >>= 1) m = fmaxf(m, __shfl_xor(m, off, 64));
    float ex = act ? expf(v - m) : 0.f;
    float s = ex;
#pragma unroll
    for (int off = 32; off; off >>= 1) s += __shfl_xor(s, off, 64);
    if (act) out[node * C_DIM + lane] = v - m - logf(s);
}

extern "C" void kernel_launch(void* const* d_in, const int* in_sizes, int n_in,
                              void* d_out, int out_size, void* d_ws, size_t ws_size,
                              hipStream_t stream) {
    const float* x  = (const float*)d_in[0];
    const int*   ei = (const int*)d_in[1];
    const float* w  = (const float*)d_in[2];
    const float* W1 = (const float*)d_in[3];
    const float* b1 = (const float*)d_in[4];
    const float* W2 = (const float*)d_in[5];
    const float* b2 = (const float*)d_in[6];
    float* out = (float*)d_out;

    float* wsf = (float*)d_ws;
    int*   wsi = (int*)d_ws;
    float* deg     = wsf + OFF_DEG;
    int*   rowStart= wsi + OFF_ROW;
    int*   cursor  = wsi + OFF_CUR;
    int*   counts  = wsi + OFF_CNT;
    int*   bsum    = wsi + OFF_BSUM;
    int*   boff    = wsi + OFF_BOFF;
    int2*  edgebuf = (int2*)(wsi + OFF_EDGE);
    float* h1      = wsf + OFF_H1;
    float* h2      = wsf + OFF_H1;      // aliases h1 (h1 dead after k_agg1)
    float* agg1    = wsf + OFF_AGG1;

    // degree + CSR build
    k_init<<<(N_NODES + 255) / 256, 256, 0, stream>>>(deg, counts);
    k_hist<<<(N_EDGES + 255) / 256, 256, 0, stream>>>(ei, w, deg, counts);
    k_dinv<<<(N_NODES + 255) / 256, 256, 0, stream>>>(deg);
    k_scan1<<<SCAN_NBLK, 256, 0, stream>>>(counts, bsum);
    k_scan2<<<1, 128, 0, stream>>>(bsum, boff, rowStart);
    k_scan3<<<SCAN_NBLK, 256, 0, stream>>>(counts, boff, rowStart, cursor);
    k_scatter<<<(N_EDGES + 255) / 256, 256, 0, stream>>>(ei, w, deg, cursor, edgebuf);

    // layer 1
    k_mm1<<<512, 256, 0, stream>>>(x, W1, h1);
    k_agg1<<<(N_NODES + 3) / 4, 256, 0, stream>>>(rowStart, edgebuf, deg, h1, agg1);

    // layer 2 (+ fused bias/log-softmax epilogue)
    k_mm2<<<512, 256, 0, stream>>>(agg1, b1, W2, h2);
    k_agg2<<<(N_NODES + 3) / 4, 256, 0, stream>>>(rowStart, edgebuf, deg, h2, b2, out);
}